// Round 1
// baseline (350.210 us; speedup 1.0000x reference)
//
#include <hip/hip_runtime.h>
#include <hip/hip_bf16.h>
#include <cstdint>
#include <cstddef>

// ResNet CG-gated basic block, MI355X gfx950.
// Pipeline: zero_borders(xpad), zero_borders(hpad), prep_w, prep_x,
//           conv_cg<1> (x_pad -> h_pad), conv_cg<2> (h_pad -> d_out w/ residual).
// Internals bf16 (MFMA), accumulation fp32. Workspace: ~57.5 MB.

typedef __attribute__((ext_vector_type(8))) short bf16x8;
typedef __attribute__((ext_vector_type(4))) float f32x4;
typedef __attribute__((ext_vector_type(8))) unsigned short u16x8;

#define HP 58
#define WP 58
#define CIN 256
#define NIMG 16

__device__ __forceinline__ unsigned short f2bf(float f) {
  unsigned int u = __float_as_uint(f);
  u += 0x7fffu + ((u >> 16) & 1u);   // RNE
  return (unsigned short)(u >> 16);
}

#define GLOAD16(gp, lp)                                                        \
  __builtin_amdgcn_global_load_lds(                                            \
      (const __attribute__((address_space(1))) void*)(gp),                     \
      (__attribute__((address_space(3))) void*)(lp), 16, 0, 0)

// ---------------------------------------------------------------- borders
__global__ void zero_borders(unsigned short* __restrict__ pad) {
  int b = blockIdx.x;              // 16*58
  int img = b / 58, yp = b - img * 58;
  int tid = threadIdx.x;
  u16x8 z = {0, 0, 0, 0, 0, 0, 0, 0};
  unsigned short* row = pad + ((size_t)(img * HP + yp)) * WP * CIN;
  if (yp == 0 || yp == HP - 1) {
    for (int i = tid; i < WP * CIN / 8; i += 256) ((u16x8*)row)[i] = z;
  } else {
    if (tid < 32) ((u16x8*)row)[tid] = z;                              // x=0
    else if (tid < 64) ((u16x8*)row)[(WP - 1) * CIN / 8 + tid - 32] = z; // x=57
  }
}

// ---------------------------------------------------------------- weights
// w OIHW fp32 -> Bt[tap][o][i] bf16
__global__ void prep_w(const float* __restrict__ wa, const float* __restrict__ wb,
                       unsigned short* __restrict__ bta, unsigned short* __restrict__ btb) {
  int id = blockIdx.x * 256 + threadIdx.x;   // 0 .. 131071
  const float* w = (id < 65536) ? wa : wb;
  unsigned short* bt = (id < 65536) ? bta : btb;
  int oi = id & 65535;
  float v[9];
#pragma unroll
  for (int t = 0; t < 9; ++t) v[t] = w[(size_t)oi * 9 + t];
#pragma unroll
  for (int t = 0; t < 9; ++t) bt[(size_t)t * 65536 + oi] = f2bf(v[t]);
}

// ---------------------------------------------------------------- x: NCHW f32 -> padded NHWC bf16
__global__ void prep_x(const float* __restrict__ x, unsigned short* __restrict__ xpad) {
  __shared__ float ld[56 * 65];
  int b = blockIdx.x;              // 16*56
  int img = b / 56, y = b - img * 56;
  int tid = threadIdx.x;
  for (int cb = 0; cb < 4; ++cb) {
    __syncthreads();
#pragma unroll
    for (int it = 0; it < 14; ++it) {
      int i = tid + it * 256;                      // 64 ch * 56 x
      int cl = i / 56, xx = i - cl * 56;
      ld[xx * 65 + cl] = x[((size_t)(img * 256 + cb * 64 + cl) * 56 + y) * 56 + xx];
    }
    __syncthreads();
#pragma unroll
    for (int it = 0; it < 14; ++it) {
      int j = tid + it * 256;
      int xx = j >> 6, c = j & 63;
      xpad[((size_t)((img * HP) + (y + 1)) * WP + (xx + 1)) * CIN + cb * 64 + c] =
          f2bf(ld[xx * 65 + c]);
    }
  }
}

// ---------------------------------------------------------------- CG conv + BN (+relu / +residual)
// block: 64 px (8x8 tile) x 128 Cout, 4 waves (2x2), K chunks of 64 ch per tap.
template <int LAYER>
__global__ __launch_bounds__(256, 2)
void conv_cg(const unsigned short* __restrict__ inp,   // [16][58][58][256] bf16
             const unsigned short* __restrict__ Bt,    // [9][256][256] bf16
             const float* __restrict__ theta,
             const float* __restrict__ gammav,
             const float* __restrict__ betav,
             const float* __restrict__ meanv,
             const float* __restrict__ varv,
             unsigned short* __restrict__ hout,        // LAYER==1
             const float* __restrict__ xres,           // LAYER==2
             float* __restrict__ dout)                 // LAYER==2
{
  __shared__ alignas(16) char smem[64 * 129 * 4];
  unsigned short* sA = (unsigned short*)smem;            // [64 px][64 ch]
  unsigned short* sB = (unsigned short*)(smem + 8192);   // [128 o][64 ch]
  float* sep = (float*)smem;                             // [64][129] epilogue

  const int tid = threadIdx.x;
  const int lane = tid & 63;
  const int wid = tid >> 6;
  const int wm = wid >> 1, wn = wid & 1;
  const int l15 = lane & 15, l4 = lane >> 4;
  const int srow = lane >> 3;     // staging: row within 8-row chunk
  const int sslot = lane & 7;     // staging: 16B slot

  int bx = blockIdx.x;
  const int ob = bx & 1; bx >>= 1;
  const int img = bx / 49;
  const int r2 = bx - img * 49;
  const int ty = r2 / 7, tx = r2 - ty * 7;
  const int y0 = ty * 8 + 1, x0 = tx * 8 + 1;   // padded coords of tile origin

  const size_t img_base = (size_t)img * (HP * WP * CIN);

  f32x4 acc[2][4], ypv[2][4];
  const f32x4 fzero = {0.f, 0.f, 0.f, 0.f};
#pragma unroll
  for (int i = 0; i < 2; ++i)
#pragma unroll
    for (int j = 0; j < 4; ++j) acc[i][j] = fzero;

  for (int phase = 0; phase < 2; ++phase) {
    const int cb_lo = phase ? 1 : 0;
    const int cb_hi = phase ? 4 : 1;
    for (int tap = 0; tap < 9; ++tap) {
      const int dy = tap / 3 - 1, dx = tap - (tap / 3) * 3 - 1;
      for (int cb = cb_lo; cb < cb_hi; ++cb) {
        // ---- stage A (64 px x 64 ch, 8KB): linear LDS dest, swizzled global src
#pragma unroll
        for (int it = 0; it < 2; ++it) {
          int chunk = wid * 2 + it;
          int row = chunk * 8 + srow;               // pixel 0..63
          int ry = row >> 3, rx = row & 7;
          int gy = y0 + ry + dy, gx = x0 + rx + dx; // always in padded bounds
          int slot = sslot ^ (row & 7);
          const unsigned short* src =
              inp + img_base + ((size_t)(gy * WP + gx)) * CIN + cb * 64 + slot * 8;
          GLOAD16(src, sA + chunk * 512);
        }
        // ---- stage B (128 o x 64 ch, 16KB)
#pragma unroll
        for (int it = 0; it < 4; ++it) {
          int chunk = wid * 4 + it;
          int o_l = chunk * 8 + srow;               // 0..127
          int slot = sslot ^ (o_l & 7);
          const unsigned short* src =
              Bt + ((size_t)(tap * 256 + ob * 128 + o_l)) * 256 + cb * 64 + slot * 8;
          GLOAD16(src, sB + chunk * 512);
        }
        __syncthreads();
        // ---- MFMA: 2 K-slices of 32
#pragma unroll
        for (int ks = 0; ks < 2; ++ks) {
          bf16x8 av[2], bv[4];
#pragma unroll
          for (int mi = 0; mi < 2; ++mi) {
            int row = wm * 32 + mi * 16 + l15;
            int sl = (ks * 4 + l4) ^ (row & 7);
            av[mi] = *(const bf16x8*)(sA + row * 64 + sl * 8);
          }
#pragma unroll
          for (int ni = 0; ni < 4; ++ni) {
            int row = wn * 64 + ni * 16 + l15;
            int sl = (ks * 4 + l4) ^ (row & 7);
            bv[ni] = *(const bf16x8*)(sB + row * 64 + sl * 8);
          }
#pragma unroll
          for (int mi = 0; mi < 2; ++mi)
#pragma unroll
            for (int ni = 0; ni < 4; ++ni)
              acc[mi][ni] = __builtin_amdgcn_mfma_f32_16x16x32_bf16(
                  av[mi], bv[ni], acc[mi][ni], 0, 0, 0);
        }
        __syncthreads();
      }
    }
    if (phase == 0) {
#pragma unroll
      for (int i = 0; i < 2; ++i)
#pragma unroll
        for (int j = 0; j < 4; ++j) { ypv[i][j] = acc[i][j]; acc[i][j] = fzero; }
    }
  }

  // ---- epilogue: gate + BN (+relu), through LDS for coalesced stores
  float th[4], sc[4], bi[4];
#pragma unroll
  for (int ni = 0; ni < 4; ++ni) {
    int o = ob * 128 + wn * 64 + ni * 16 + l15;
    th[ni] = theta[o];
    float inv = gammav[o] * rsqrtf(varv[o] + 1e-5f);
    sc[ni] = inv;
    bi[ni] = betav[o] - meanv[o] * inv;
  }
#pragma unroll
  for (int mi = 0; mi < 2; ++mi)
#pragma unroll
    for (int ni = 0; ni < 4; ++ni) {
      int colL = wn * 64 + ni * 16 + l15;   // col within 128
#pragma unroll
      for (int q = 0; q < 4; ++q) {
        int m = wm * 32 + mi * 16 + l4 * 4 + q;   // pixel 0..63
        float yp = ypv[mi][ni][q], yr = acc[mi][ni][q];
        float d = 1.f / (1.f + __expf(-2.f * (yp - th[ni])));
        float v = (yp + d * yr) * sc[ni] + bi[ni];
        if (LAYER == 1) v = fmaxf(v, 0.f);
        sep[m * 129 + colL] = v;
      }
    }
  __syncthreads();

  if (LAYER == 1) {
    // h_pad interior, NHWC bf16, 16B per store, coalesced per pixel
#pragma unroll
    for (int it = 0; it < 4; ++it) {
      int j = tid + it * 256;                 // 64 px * 16 (o-octets)
      int p = j >> 4, o8 = (j & 15) * 8;
      int ry = p >> 3, rx = p & 7;
      u16x8 tv;
#pragma unroll
      for (int e = 0; e < 8; ++e) tv[e] = f2bf(sep[p * 129 + o8 + e]);
      unsigned short* dst =
          hout + img_base + ((size_t)((y0 + ry) * WP + (x0 + rx))) * CIN + ob * 128 + o8;
      *(u16x8*)dst = tv;
    }
  } else {
    // NCHW fp32 + residual + relu, 8 contiguous x per (o,ry)
#pragma unroll
    for (int it = 0; it < 4; ++it) {
      int j = tid + it * 256;                 // 128 o * 8 ry
      int o = j >> 3, ry = j & 7;
      int oc = ob * 128 + o;
      size_t gb = ((size_t)((img * 256 + oc) * 56 + (y0 - 1 + ry))) * 56 + (x0 - 1);
      const float4 xa = *(const float4*)(xres + gb);
      const float4 xb = *(const float4*)(xres + gb + 4);
      float4 ra, rb;
      ra.x = fmaxf(xa.x + sep[(ry * 8 + 0) * 129 + o], 0.f);
      ra.y = fmaxf(xa.y + sep[(ry * 8 + 1) * 129 + o], 0.f);
      ra.z = fmaxf(xa.z + sep[(ry * 8 + 2) * 129 + o], 0.f);
      ra.w = fmaxf(xa.w + sep[(ry * 8 + 3) * 129 + o], 0.f);
      rb.x = fmaxf(xb.x + sep[(ry * 8 + 4) * 129 + o], 0.f);
      rb.y = fmaxf(xb.y + sep[(ry * 8 + 5) * 129 + o], 0.f);
      rb.z = fmaxf(xb.z + sep[(ry * 8 + 6) * 129 + o], 0.f);
      rb.w = fmaxf(xb.w + sep[(ry * 8 + 7) * 129 + o], 0.f);
      *(float4*)(dout + gb) = ra;
      *(float4*)(dout + gb + 4) = rb;
    }
  }
}

// ----------------------------------------------------------------
extern "C" void kernel_launch(void* const* d_in, const int* in_sizes, int n_in,
                              void* d_out, int out_size, void* d_ws, size_t ws_size,
                              hipStream_t stream) {
  const float* x    = (const float*)d_in[0];
  const float* w_a  = (const float*)d_in[1];
  const float* th_a = (const float*)d_in[2];
  const float* ga_a = (const float*)d_in[3];
  const float* be_a = (const float*)d_in[4];
  const float* mu_a = (const float*)d_in[5];
  const float* va_a = (const float*)d_in[6];
  const float* w_b  = (const float*)d_in[7];
  const float* th_b = (const float*)d_in[8];
  const float* ga_b = (const float*)d_in[9];
  const float* be_b = (const float*)d_in[10];
  const float* mu_b = (const float*)d_in[11];
  const float* va_b = (const float*)d_in[12];
  float* out = (float*)d_out;

  // workspace layout
  const size_t PAD_BYTES = (size_t)NIMG * HP * WP * CIN * 2;  // 27,557,888 -> round up
  char* ws = (char*)d_ws;
  unsigned short* xpad = (unsigned short*)ws;
  unsigned short* hpad = (unsigned short*)(ws + 27558912);
  unsigned short* bta  = (unsigned short*)(ws + 2 * 27558912);
  unsigned short* btb  = (unsigned short*)(ws + 2 * 27558912 + 1179648);
  (void)PAD_BYTES; (void)ws_size; (void)in_sizes; (void)n_in; (void)out_size;

  hipLaunchKernelGGL(zero_borders, dim3(NIMG * HP), dim3(256), 0, stream, xpad);
  hipLaunchKernelGGL(zero_borders, dim3(NIMG * HP), dim3(256), 0, stream, hpad);
  hipLaunchKernelGGL(prep_w, dim3(512), dim3(256), 0, stream, w_a, w_b, bta, btb);
  hipLaunchKernelGGL(prep_x, dim3(NIMG * 56), dim3(256), 0, stream, x, xpad);

  hipLaunchKernelGGL((conv_cg<1>), dim3(NIMG * 49 * 2), dim3(256), 0, stream,
                     xpad, bta, th_a, ga_a, be_a, mu_a, va_a,
                     hpad, (const float*)nullptr, (float*)nullptr);
  hipLaunchKernelGGL((conv_cg<2>), dim3(NIMG * 49 * 2), dim3(256), 0, stream,
                     hpad, btb, th_b, ga_b, be_b, mu_b, va_b,
                     (unsigned short*)nullptr, x, out);
}

// Round 2
// 320.588 us; speedup vs baseline: 1.0924x; 1.0924x over previous
//
#include <hip/hip_runtime.h>
#include <hip/hip_bf16.h>
#include <cstdint>
#include <cstddef>

// ResNet CG-gated basic block, MI355X gfx950.
// conv as implicit GEMM with LDS-resident A-patch (10x10x64ch per wave, reused
// across all 9 taps) and double-buffered streamed B (8KB per tap chunk).
// Block = 4 waves; wave = one 8x8 px tile x 64 outs. 2 blocks/CU (LDS 67.6KB).
// Internals bf16 (MFMA 16x16x32), fp32 accum. Workspace ~57.5 MB.

typedef __attribute__((ext_vector_type(8))) short bf16x8;
typedef __attribute__((ext_vector_type(4))) float f32x4;
typedef __attribute__((ext_vector_type(8))) unsigned short u16x8;

#define HP 58
#define WP 58
#define CIN 256
#define NIMG 16

__device__ __forceinline__ unsigned short f2bf(float f) {
  unsigned int u = __float_as_uint(f);
  u += 0x7fffu + ((u >> 16) & 1u);   // RNE
  return (unsigned short)(u >> 16);
}

#define GLOAD16(gp, lp)                                                        \
  __builtin_amdgcn_global_load_lds(                                            \
      (const __attribute__((address_space(1))) void*)(gp),                     \
      (__attribute__((address_space(3))) void*)(lp), 16, 0, 0)

// ---------------------------------------------------------------- hpad borders
__global__ void zero_borders(unsigned short* __restrict__ pad) {
  int b = blockIdx.x;              // 16*58
  int img = b / 58, yp = b - img * 58;
  int tid = threadIdx.x;
  u16x8 z = {0, 0, 0, 0, 0, 0, 0, 0};
  unsigned short* row = pad + ((size_t)(img * HP + yp)) * WP * CIN;
  if (yp == 0 || yp == HP - 1) {
    for (int i = tid; i < WP * CIN / 8; i += 256) ((u16x8*)row)[i] = z;
  } else {
    if (tid < 32) ((u16x8*)row)[tid] = z;                                // x=0
    else if (tid < 64) ((u16x8*)row)[(WP - 1) * CIN / 8 + tid - 32] = z; // x=57
  }
}

// ---------------------------------------------------------------- weights
// w OIHW f32 -> Bt[tap][cb][256 o][64 c] bf16 (contiguous 32KB per (tap,cb))
__global__ void prep_w(const float* __restrict__ wa, const float* __restrict__ wb,
                       unsigned short* __restrict__ bta, unsigned short* __restrict__ btb) {
  int id = blockIdx.x * 256 + threadIdx.x;   // 0 .. 131071
  const float* w = (id < 65536) ? wa : wb;
  unsigned short* bt = (id < 65536) ? bta : btb;
  int oi = id & 65535;
  int o = oi >> 8, i = oi & 255;
  int cb = i >> 6, c = i & 63;
  float v[9];
#pragma unroll
  for (int t = 0; t < 9; ++t) v[t] = w[(size_t)oi * 9 + t];
#pragma unroll
  for (int t = 0; t < 9; ++t)
    bt[((size_t)((t * 4 + cb) * 256 + o)) * 64 + c] = f2bf(v[t]);
}

// ------------------------------------------ x: NCHW f32 -> padded NHWC bf16 (+borders)
__global__ void prep_x(const float* __restrict__ x, unsigned short* __restrict__ xpad) {
  __shared__ float ld[56 * 65];
  int b = blockIdx.x;              // 16*58 padded rows
  int img = b / 58, y = b - img * 58;
  int tid = threadIdx.x;
  unsigned short* row = xpad + ((size_t)(img * HP + y)) * WP * CIN;
  u16x8 z = {0, 0, 0, 0, 0, 0, 0, 0};
  if (y == 0 || y == HP - 1) {
#pragma unroll
    for (int it = 0; it < 8; ++it) {
      int i = it * 256 + tid;
      if (i < WP * CIN / 8) ((u16x8*)row)[i] = z;
    }
    return;
  }
  if (tid < 32) ((u16x8*)row)[tid] = z;
  else if (tid < 64) ((u16x8*)row)[(WP - 1) * CIN / 8 + tid - 32] = z;
  int ys = y - 1;
  for (int cb = 0; cb < 4; ++cb) {
    __syncthreads();
#pragma unroll
    for (int it = 0; it < 14; ++it) {
      int i = tid + it * 256;                      // 64 ch * 56 x
      int cl = i / 56, xx = i - cl * 56;
      ld[xx * 65 + cl] = x[((size_t)(img * 256 + cb * 64 + cl) * 56 + ys) * 56 + xx];
    }
    __syncthreads();
#pragma unroll
    for (int it = 0; it < 14; ++it) {
      int j = tid + it * 256;
      int xx = j >> 6, c = j & 63;
      row[(xx + 1) * CIN + cb * 64 + c] = f2bf(ld[xx * 65 + c]);
    }
  }
}

// ---------------------------------------------------------------- CG conv + BN
// grid = 196 px-groups * 4 out-quarters = 784 blocks, 256 threads (4 waves).
// Wave: one 8x8 tile (64px) x 64 outs; A patch 10x10x64ch resident per cb.
__device__ __forceinline__ void stage_b(const unsigned short* __restrict__ cbase,
                                        unsigned short* dst, int wid, int lane) {
#pragma unroll
  for (int it = 0; it < 2; ++it) {
    int d = (wid * 2 + it) * 64 + lane;          // unit 0..511 (16B units)
    int o = d >> 3, s = d & 7;
    const unsigned short* src = cbase + o * 64 + ((s ^ (o & 7)) << 3);
    GLOAD16(src, dst + (wid * 2 + it) * 512);
  }
}

template <int LAYER>
__global__ __launch_bounds__(256, 2)
void conv_cg(const unsigned short* __restrict__ inp,   // [16][58][58][256] bf16
             const unsigned short* __restrict__ Bt,    // [9][4][256][64] bf16
             const float* __restrict__ theta,
             const float* __restrict__ gammav,
             const float* __restrict__ betav,
             const float* __restrict__ meanv,
             const float* __restrict__ varv,
             unsigned short* __restrict__ hout,        // LAYER==1
             const float* __restrict__ xres,           // LAYER==2
             float* __restrict__ dout)                 // LAYER==2
{
  __shared__ alignas(16) char smem[67584];   // A: 4*12800 | B: 2*8192
  const int tid = threadIdx.x;
  const int lane = tid & 63;
  const int wid = tid >> 6;
  const int l15 = lane & 15, l4 = lane >> 4;

  int bx = blockIdx.x;
  const int oq = bx & 3;
  const int pxg = bx >> 2;
  const int tile = pxg * 4 + wid;            // 0..783, per-wave 8x8 tile
  const int img = tile / 49;
  const int rr = tile - img * 49;
  const int ty = rr / 7, tx = rr - ty * 7;
  const int y0 = ty * 8 + 1, x0 = tx * 8 + 1;
  const size_t img_base = (size_t)img * (HP * WP * CIN);

  unsigned short* sAw = (unsigned short*)smem + wid * 6400;   // own patch 12.8KB
  unsigned short* sB0 = (unsigned short*)(smem + 51200);
  unsigned short* sB1 = (unsigned short*)(smem + 59392);

  // BN + gate params for this wave's 64 outs
  float th[4], sc[4], bi[4];
#pragma unroll
  for (int ni = 0; ni < 4; ++ni) {
    int o = oq * 64 + ni * 16 + l15;
    th[ni] = theta[o];
    float inv = gammav[o] * rsqrtf(varv[o] + 1e-5f);
    sc[ni] = inv;
    bi[ni] = betav[o] - meanv[o] * inv;
  }

  f32x4 acc[4][4], ypv[4][4];
  const f32x4 fzero = {0.f, 0.f, 0.f, 0.f};
#pragma unroll
  for (int i = 0; i < 4; ++i)
#pragma unroll
    for (int j = 0; j < 4; ++j) { acc[i][j] = fzero; ypv[i][j] = fzero; }

  for (int cb = 0; cb < 4; ++cb) {
    // ---- stage A patch slice (10x10 px x 64ch), swizzled source, linear dest
    {
      const unsigned short* abase = inp + img_base + cb * 64;
#pragma unroll
      for (int it = 0; it < 13; ++it) {
        int v = it * 64 + lane;                 // 16B unit within patch
        if (v < 800) {
          int ppx = v >> 3, s = v & 7;
          int py = ppx / 10, pxx = ppx - py * 10;
          const unsigned short* src = abase +
              ((size_t)((y0 - 1 + py) * WP + (x0 - 1 + pxx))) * CIN +
              ((s ^ (ppx & 7)) << 3);
          GLOAD16(src, sAw + it * 512);
        }
      }
    }
    // ---- stage B(tap 0)
    stage_b(Bt + ((size_t)((0 * 4 + cb) * 256 + oq * 64)) * 64, sB0, wid, lane);
    __syncthreads();

#pragma unroll
    for (int tap = 0; tap < 9; ++tap) {
      if (tap < 8) {   // prefetch next B chunk into other buffer (T3: issue early)
        unsigned short* nb = ((tap + 1) & 1) ? sB1 : sB0;
        stage_b(Bt + ((size_t)(((tap + 1) * 4 + cb) * 256 + oq * 64)) * 64,
                nb, wid, lane);
      }
      const unsigned short* bb = (tap & 1) ? sB1 : sB0;
      const int dy = tap / 3 - 1, dxx = tap - (tap / 3) * 3 - 1;
#pragma unroll
      for (int ks = 0; ks < 2; ++ks) {
        bf16x8 av[4], bv[4];
#pragma unroll
        for (int mi = 0; mi < 4; ++mi) {
          int ry = mi * 2 + (l15 >> 3);
          int ppx = (ry + dy + 1) * 10 + (l15 & 7) + dxx + 1;
          av[mi] = *(const bf16x8*)(sAw + ppx * 64 +
                                    (((ks * 4 + l4) ^ (ppx & 7)) << 3));
        }
#pragma unroll
        for (int ni = 0; ni < 4; ++ni) {
          int ol = ni * 16 + l15;
          bv[ni] = *(const bf16x8*)(bb + ol * 64 +
                                    (((ks * 4 + l4) ^ (ol & 7)) << 3));
        }
#pragma unroll
        for (int mi = 0; mi < 4; ++mi)
#pragma unroll
          for (int ni = 0; ni < 4; ++ni)
            acc[mi][ni] = __builtin_amdgcn_mfma_f32_16x16x32_bf16(
                av[mi], bv[ni], acc[mi][ni], 0, 0, 0);
      }
      __syncthreads();
    }
    if (cb == 0) {    // yp done (base 64 channels, all taps)
#pragma unroll
      for (int i = 0; i < 4; ++i)
#pragma unroll
        for (int j = 0; j < 4; ++j) { ypv[i][j] = acc[i][j]; acc[i][j] = fzero; }
    }
  }

  // ---- epilogue: gate + BN (+relu / +residual), 2 rounds of 32 px through LDS
  float* sep = (float*)smem + wid * 2176;     // [32 px][68] per wave
#pragma unroll
  for (int r = 0; r < 2; ++r) {
    __syncthreads();
#pragma unroll
    for (int mh = 0; mh < 2; ++mh) {
      int mi = r * 2 + mh;
#pragma unroll
      for (int ni = 0; ni < 4; ++ni)
#pragma unroll
        for (int q = 0; q < 4; ++q) {
          int rowl = mh * 16 + l4 * 4 + q;     // 0..31
          float yp = ypv[mi][ni][q], yr = acc[mi][ni][q];
          float dg = 1.f / (1.f + __expf(-2.f * (yp - th[ni])));
          float v = (yp + dg * yr) * sc[ni] + bi[ni];
          if (LAYER == 1) v = fmaxf(v, 0.f);
          sep[rowl * 68 + ni * 16 + l15] = v;
        }
    }
    __syncthreads();
    if (LAYER == 1) {
#pragma unroll
      for (int it = 0; it < 4; ++it) {
        int u = it * 64 + lane;                // 32px * 8 octet-units
        int pxl = u >> 3, s = u & 7;
        int m = r * 32 + pxl;
        int ry = m >> 3, rx = m & 7;
        u16x8 tv;
#pragma unroll
        for (int e = 0; e < 8; ++e) tv[e] = f2bf(sep[pxl * 68 + s * 8 + e]);
        *(u16x8*)(hout + img_base +
                  ((size_t)((y0 + ry) * WP + (x0 + rx))) * CIN + oq * 64 + s * 8) = tv;
      }
    } else {
#pragma unroll
      for (int it = 0; it < 8; ++it) {
        int idx = it * 64 + lane;              // 64oc * 4rows * 2halves
        int oc = idx >> 3, t = idx & 7;
        int row4 = t >> 1, half = t & 1;
        int pxl = row4 * 8 + half * 4;
        int gy = y0 - 1 + r * 4 + row4, gx = x0 - 1 + half * 4;
        size_t gb = ((size_t)(img * 256 + oq * 64 + oc) * 56 + gy) * 56 + gx;
        const float4 xa = *(const float4*)(xres + gb);
        float4 o4;
        o4.x = fmaxf(xa.x + sep[(pxl + 0) * 68 + oc], 0.f);
        o4.y = fmaxf(xa.y + sep[(pxl + 1) * 68 + oc], 0.f);
        o4.z = fmaxf(xa.z + sep[(pxl + 2) * 68 + oc], 0.f);
        o4.w = fmaxf(xa.w + sep[(pxl + 3) * 68 + oc], 0.f);
        *(float4*)(dout + gb) = o4;
      }
    }
  }
}

// ----------------------------------------------------------------
extern "C" void kernel_launch(void* const* d_in, const int* in_sizes, int n_in,
                              void* d_out, int out_size, void* d_ws, size_t ws_size,
                              hipStream_t stream) {
  const float* x    = (const float*)d_in[0];
  const float* w_a  = (const float*)d_in[1];
  const float* th_a = (const float*)d_in[2];
  const float* ga_a = (const float*)d_in[3];
  const float* be_a = (const float*)d_in[4];
  const float* mu_a = (const float*)d_in[5];
  const float* va_a = (const float*)d_in[6];
  const float* w_b  = (const float*)d_in[7];
  const float* th_b = (const float*)d_in[8];
  const float* ga_b = (const float*)d_in[9];
  const float* be_b = (const float*)d_in[10];
  const float* mu_b = (const float*)d_in[11];
  const float* va_b = (const float*)d_in[12];
  float* out = (float*)d_out;

  char* ws = (char*)d_ws;
  unsigned short* xpad = (unsigned short*)ws;
  unsigned short* hpad = (unsigned short*)(ws + 27558912);
  unsigned short* bta  = (unsigned short*)(ws + 2 * 27558912);
  unsigned short* btb  = (unsigned short*)(ws + 2 * 27558912 + 1179648);
  (void)ws_size; (void)in_sizes; (void)n_in; (void)out_size;

  hipLaunchKernelGGL(zero_borders, dim3(NIMG * HP), dim3(256), 0, stream, hpad);
  hipLaunchKernelGGL(prep_w, dim3(512), dim3(256), 0, stream, w_a, w_b, bta, btb);
  hipLaunchKernelGGL(prep_x, dim3(NIMG * HP), dim3(256), 0, stream, x, xpad);

  hipLaunchKernelGGL((conv_cg<1>), dim3(784), dim3(256), 0, stream,
                     xpad, bta, th_a, ga_a, be_a, mu_a, va_a,
                     hpad, (const float*)nullptr, (float*)nullptr);
  hipLaunchKernelGGL((conv_cg<2>), dim3(784), dim3(256), 0, stream,
                     hpad, btb, th_b, ga_b, be_b, mu_b, va_b,
                     (unsigned short*)nullptr, x, out);
}